// Round 7
// baseline (171.469 us; speedup 1.0000x reference)
//
#include <hip/hip_runtime.h>
#include <stdint.h>

#define BB 16
#define CC 4
#define HH 768
#define WW 768
#define HW (HH * WW)          // 589824
#define NPIX (BB * HW)        // 9437184
#define NIMG (BB * (CC - 1))  // 48
#define BEST_STRIDE 16        // ull entries -> 128 B per (img,class)

#define TS 64                 // tile side
#define TPI (WW / TS)         // 12 tiles per image dim
#define TILES_PER_IMG (TPI * TPI)  // 144
#define TPIX (TS * TS)        // 4096
#define CCL_TPB 256

typedef unsigned long long ull;

// ---------------- global union-find (border merges only) ----------------

__device__ __forceinline__ int find_root(int* P, int i) {
    int p = P[i];
    while (p != i) {
        int gp = P[p];
        P[i] = gp;   // path halving (benign race)
        i = p;
        p = gp;
    }
    return i;
}

__device__ __forceinline__ void merge(int* P, int a, int b) {
    a = find_root(P, a);
    b = find_root(P, b);
    while (a != b) {
        if (a < b) { int t = a; a = b; b = t; }  // a = larger root
        int old = atomicCAS(&P[a], a, b);        // attach larger under smaller
        if (old == a) return;
        a = find_root(P, old);
        b = find_root(P, b);
    }
}

// ---------------- LDS union-find ----------------

__device__ __forceinline__ int lfind(int* P, int i) {
    int p = P[i];
    while (p != i) {
        int gp = P[p];
        P[i] = gp;
        i = p;
        p = gp;
    }
    return i;
}

__device__ __forceinline__ void lmerge(int* P, int a, int b) {
    a = lfind(P, a);
    b = lfind(P, b);
    while (a != b) {
        if (a < b) { int t = a; a = b; b = t; }
        int old = atomicCAS(&P[a], a, b);
        if (old == a) return;
        a = lfind(P, old);
        b = lfind(P, b);
    }
}

__device__ __forceinline__ ull umax64(ull a, ull b) { return a > b ? a : b; }

// ---------------- kernels ----------------

// pure streaming: argmax over 4 channels -> labels (uint8). also inits best[].
__global__ void k_argmax(const float* __restrict__ pred,
                         uint8_t* __restrict__ labels,
                         ull* __restrict__ best) {
    int q = blockIdx.x * blockDim.x + threadIdx.x;
    if (q < NIMG * BEST_STRIDE) best[q] = 0ull;
    if (q >= NPIX / 4) return;
    int t = q * 4;
    int b = t / HW;
    int i = t - b * HW;
    const float* p = pred + (size_t)b * CC * HW + i;
    float4 v0 = *(const float4*)&p[0];
    float4 v1 = *(const float4*)&p[HW];
    float4 v2 = *(const float4*)&p[2 * HW];
    float4 v3 = *(const float4*)&p[3 * HW];
    const float* a0 = &v0.x; const float* a1 = &v1.x;
    const float* a2 = &v2.x; const float* a3 = &v3.x;
    uchar4 lout;
    uint8_t* lj = &lout.x;
    #pragma unroll
    for (int j = 0; j < 4; ++j) {
        int lab = 0;
        float bv = a0[j];
        if (a1[j] > bv) { bv = a1[j]; lab = 1; }
        if (a2[j] > bv) { bv = a2[j]; lab = 2; }
        if (a3[j] > bv) { bv = a3[j]; lab = 3; }
        lj[j] = (uint8_t)lab;
    }
    *(uchar4*)&labels[t] = lout;
}

// per 64x64 tile: run-based local CCL in LDS; run-based counting into sp high bits.
// writes: parent[pix] = global raster idx of tile-local root (-1 bg);
//         counts[pix] = local component size at fg local-root pixels, 0 elsewhere.
__global__ __launch_bounds__(CCL_TPB) void k_ccl(
        const uint8_t* __restrict__ labels,
        int* __restrict__ parent,
        uint32_t* __restrict__ counts) {
    __shared__ __align__(16) int sp[TPIX];       // 16 KB parent; roots gain count<<16
    __shared__ __align__(16) uint8_t slab[TPIX]; // 4 KB labels (live whole kernel)

    const int tid = (int)threadIdx.x;
    const int img = blockIdx.x / TILES_PER_IMG;
    const int tile = blockIdx.x % TILES_PER_IMG;
    const int tr = (tile / TPI) * TS;
    const int tc = (tile % TPI) * TS;
    const int imgbase = img * HW;

    // phase 0: load tile labels into LDS, 4 px/thread
    for (int k = 0; k < TPIX; k += CCL_TPB * 4) {
        int li = k + tid * 4;
        int gi = imgbase + (tr + (li >> 6)) * WW + tc + (li & 63);
        *(uchar4*)&slab[li] = *(const uchar4*)&labels[gi];
    }
    __syncthreads();

    const int c = tid & 63;  // wave lane == column within row

    // phase 1: horizontal runs via ballot; sp[pix] = run-start (fg), self (bg)
    #pragma unroll 1
    for (int it = 0; it < TPIX / CCL_TPB; ++it) {
        int li = it * CCL_TPB + tid;
        int lab = slab[li];
        int labL = __shfl_up(lab, 1, 64);
        bool isStart = lab && (c == 0 || labL != lab);
        ull mask = __ballot(isStart);
        int v = li;
        if (lab) {
            ull mle = mask & (~0ull >> (63 - c));
            v = (li & ~63) + (63 - __clzll(mle));
        }
        sp[li] = v;
    }
    __syncthreads();

    // phase 2: vertical merges, one per run-contact segment (crack criterion)
    #pragma unroll 1
    for (int it = 0; it < TPIX / CCL_TPB; ++it) {
        int li = it * CCL_TPB + tid;
        int lab = slab[li];
        int labU = (li >= TS) ? (int)slab[li - TS] : 0;
        int labL = __shfl_up(lab, 1, 64);
        int labUL = __shfl_up(labU, 1, 64);
        if (lab && labU == lab) {
            if (c == 0 || !(labL == lab && labUL == lab))
                lmerge(sp, li, li - TS);
        }
    }
    __syncthreads();

    // phase 3: flatten every fg pixel to its local root (divergent but short chains)
    #pragma unroll 1
    for (int it = 0; it < TPIX / CCL_TPB; ++it) {
        int li = it * CCL_TPB + tid;
        if (slab[li]) {
            int p = sp[li];
            while (true) { int pp = sp[p]; if (pp == p) break; p = pp; }
            sp[li] = p;
        }
    }
    __syncthreads();

    // phase 4: run-based counting into sp high bits (one atomic per fg run)
    #pragma unroll 1
    for (int it = 0; it < TPIX / CCL_TPB; ++it) {
        int li = it * CCL_TPB + tid;
        int lab = slab[li];
        int labL = __shfl_up(lab, 1, 64);
        bool isStart = lab && (c == 0 || labL != lab);
        bool isEnd = lab && (c == 63 || (int)slab[li + 1] != lab);
        ull endmask = __ballot(isEnd);
        if (isStart) {
            ull mge = endmask & (~0ull << c);
            int epos = __ffsll((long long)mge) - 1;
            int runlen = epos - c + 1;
            int root = sp[li] & 0xFFFF;
            atomicAdd((unsigned int*)&sp[root], (unsigned int)runlen << 16);
        }
    }
    __syncthreads();

    // phase 5: write parent & counts, 4 px/thread
    for (int k = 0; k < TPIX; k += CCL_TPB * 4) {
        int li = k + tid * 4;
        int gi = imgbase + (tr + (li >> 6)) * WW + tc + (li & 63);
        uchar4 lv = *(const uchar4*)&slab[li];
        int4 sv = *(const int4*)&sp[li];
        const uint8_t* lj = &lv.x;
        const int* sj = &sv.x;
        int4 pout; uint4 cout;
        int* pj = &pout.x; uint32_t* cj = &cout.x;
        #pragma unroll
        for (int j = 0; j < 4; ++j) {
            int root = sj[j] & 0xFFFF;
            if (lj[j]) {
                pj[j] = imgbase + (tr + (root >> 6)) * WW + tc + (root & 63);
                cj[j] = (root == li + j) ? ((uint32_t)sj[j] >> 16) : 0u;
            } else {
                pj[j] = -1;
                cj[j] = 0u;
            }
        }
        *(int4*)&parent[gi] = pout;
        *(uint4*)&counts[gi] = cout;
    }
}

// merge across tile borders only
#define VEDGES ((TPI - 1) * HH)             // 8448
#define EDGES_PER_IMG (2 * (TPI - 1) * HH)  // 16896
__global__ void k_border_merge(const uint8_t* __restrict__ labels, int* parent) {
    int t = blockIdx.x * blockDim.x + threadIdx.x;
    if (t >= BB * EDGES_PER_IMG) return;
    int img = t / EDGES_PER_IMG;
    int e = t % EDGES_PER_IMG;
    int a, b;
    if (e < VEDGES) {
        int j = e / HH, r = e % HH;
        int c = j * TS + TS - 1;
        a = r * WW + c;
        b = a + 1;
    } else {
        e -= VEDGES;
        int j = e / WW, c = e % WW;
        int r = j * TS + TS - 1;
        a = r * WW + c;
        b = a + WW;
    }
    int ga = img * HW + a, gb = img * HW + b;
    uint8_t la = labels[ga];
    if (la && labels[gb] == la) merge(parent, ga, gb);
}

// for each local root (counts>0): chase to global root, point parent directly at it,
// move its local count there (atomics only for merged roots)
__global__ void k_compress(int* __restrict__ parent, uint32_t* __restrict__ counts) {
    int t = blockIdx.x * blockDim.x + threadIdx.x;
    if (t >= NPIX) return;
    uint32_t cnt = counts[t];
    if (!cnt) return;           // not a local root
    int g = parent[t];
    if (g == t) return;         // already a global root
    while (true) { int pg = parent[g]; if (pg == g) break; g = pg; }
    parent[t] = g;
    atomicAdd(&counts[g], cnt);
    counts[t] = 0;
}

// per (img, class) max over roots of key = (count<<32) | ~root_index
#define BEST_BLK_PER_IMG 144
#define BEST_TPB 256
#define BEST_PIX_PER_BLK (HW / BEST_BLK_PER_IMG)  // 4096
__global__ void k_best(const uint8_t* __restrict__ labels,
                       const uint32_t* __restrict__ counts,
                       ull* __restrict__ best) {
    __shared__ ull sw[(BEST_TPB / 64) * 3];
    int img = blockIdx.x / BEST_BLK_PER_IMG;
    int chunk = blockIdx.x % BEST_BLK_PER_IMG;
    int base = img * HW + chunk * BEST_PIX_PER_BLK;

    ull l0 = 0, l1 = 0, l2 = 0;
    for (int k = 0; k < BEST_PIX_PER_BLK; k += BEST_TPB * 4) {
        int t = base + k + (int)threadIdx.x * 4;
        uint4 cv = *(const uint4*)&counts[t];
        if (cv.x | cv.y | cv.z | cv.w) {
            uchar4 lv = *(const uchar4*)&labels[t];
            uint32_t cs[4] = {cv.x, cv.y, cv.z, cv.w};
            uint8_t ls[4] = {lv.x, lv.y, lv.z, lv.w};
            #pragma unroll
            for (int j = 0; j < 4; ++j) {
                if (cs[j]) {
                    int cc = (int)ls[j] - 1;
                    ull key = ((ull)cs[j] << 32) | (ull)(~(uint32_t)(t + j));
                    if (cc == 0) l0 = umax64(l0, key);
                    else if (cc == 1) l1 = umax64(l1, key);
                    else l2 = umax64(l2, key);
                }
            }
        }
    }
    #pragma unroll
    for (int m = 1; m < 64; m <<= 1) {
        l0 = umax64(l0, __shfl_xor(l0, m, 64));
        l1 = umax64(l1, __shfl_xor(l1, m, 64));
        l2 = umax64(l2, __shfl_xor(l2, m, 64));
    }
    int lane = threadIdx.x & 63;
    int wid = threadIdx.x >> 6;
    if (lane == 0) { sw[wid * 3 + 0] = l0; sw[wid * 3 + 1] = l1; sw[wid * 3 + 2] = l2; }
    __syncthreads();
    if (threadIdx.x < 3) {
        ull m = 0;
        for (int w = 0; w < BEST_TPB / 64; ++w) m = umax64(m, sw[w * 3 + threadIdx.x]);
        if (m) atomicMax(&best[(img * 3 + (int)threadIdx.x) * BEST_STRIDE], m);
    }
}

// final output: global root = parent[parent[t]] (local roots point at global roots)
__global__ void k_output(const uint8_t* __restrict__ labels,
                         const int* __restrict__ parent,
                         const ull* __restrict__ best,
                         float* __restrict__ out) {
    int q = blockIdx.x * blockDim.x + threadIdx.x;
    if (q >= NPIX / 4) return;
    int t = q * 4;
    int b = t / HW;
    int i = t - b * HW;
    uchar4 lv = *(const uchar4*)&labels[t];
    int4 pv = *(const int4*)&parent[t];
    int root[3];
    root[0] = (int)(~(uint32_t)best[(b * 3 + 0) * BEST_STRIDE]);
    root[1] = (int)(~(uint32_t)best[(b * 3 + 1) * BEST_STRIDE]);
    root[2] = (int)(~(uint32_t)best[(b * 3 + 2) * BEST_STRIDE]);

    uint8_t ls[4] = {lv.x, lv.y, lv.z, lv.w};
    int ps[4] = {pv.x, pv.y, pv.z, pv.w};
    float fg[4];
    #pragma unroll
    for (int j = 0; j < 4; ++j) {
        int g = -1;
        if (ps[j] >= 0) g = parent[ps[j]];  // tile-local -> cache hit
        fg[j] = (ls[j] && g == root[ls[j] - 1]) ? 1.0f : 0.0f;
    }

    float4 o0, o1, o2, o3;
    float* c0 = &o0.x; float* c1 = &o1.x; float* c2 = &o2.x; float* c3 = &o3.x;
    #pragma unroll
    for (int j = 0; j < 4; ++j) {
        c0[j] = 1.0f - fg[j];
        c1[j] = (ls[j] == 1) ? fg[j] : 0.0f;
        c2[j] = (ls[j] == 2) ? fg[j] : 0.0f;
        c3[j] = (ls[j] == 3) ? fg[j] : 0.0f;
    }
    float* o = out + (size_t)b * CC * HW + i;
    *(float4*)&o[0] = o0;
    *(float4*)&o[HW] = o1;
    *(float4*)&o[2 * HW] = o2;
    *(float4*)&o[3 * HW] = o3;
}

// ---------------- launch ----------------

extern "C" void kernel_launch(void* const* d_in, const int* in_sizes, int n_in,
                              void* d_out, int out_size, void* d_ws, size_t ws_size,
                              hipStream_t stream) {
    const float* pred = (const float*)d_in[0];
    float* out = (float*)d_out;

    uint8_t* labels = (uint8_t*)d_ws;                            // NPIX bytes
    int* parent = (int*)((char*)d_ws + NPIX);                    // NPIX*4 bytes
    ull* best = (ull*)((char*)d_ws + NPIX + (size_t)NPIX * 4);   // NIMG*BEST_STRIDE*8
    uint32_t* counts = (uint32_t*)d_out;  // reuse d_out; overwritten by k_output

    const int TPB = 256;

    k_argmax<<<(NPIX / 4 + TPB - 1) / TPB, TPB, 0, stream>>>(pred, labels, best);
    k_ccl<<<BB * TILES_PER_IMG, CCL_TPB, 0, stream>>>(labels, parent, counts);
    k_border_merge<<<(BB * EDGES_PER_IMG + TPB - 1) / TPB, TPB, 0, stream>>>(labels, parent);
    k_compress<<<(NPIX + TPB - 1) / TPB, TPB, 0, stream>>>(parent, counts);
    k_best<<<BB * BEST_BLK_PER_IMG, BEST_TPB, 0, stream>>>(labels, counts, best);
    k_output<<<(NPIX / 4 + TPB - 1) / TPB, TPB, 0, stream>>>(labels, parent, best, out);
}

// Round 8
// 154.187 us; speedup vs baseline: 1.1121x; 1.1121x over previous
//
#include <hip/hip_runtime.h>
#include <stdint.h>

#define BB 16
#define CC 4
#define HH 768
#define WW 768
#define HW (HH * WW)          // 589824
#define NPIX (BB * HW)        // 9437184
#define NIMG (BB * (CC - 1))  // 48
#define BEST_STRIDE 16        // ull entries -> 128 B per (img,class)

#define TS 64                 // tile side
#define TPI (WW / TS)         // 12 tiles per image dim
#define TILES_PER_IMG (TPI * TPI)  // 144
#define TPIX (TS * TS)        // 4096
#define CCL_TPB 256

typedef unsigned long long ull;

// ---------------- global union-find (border merges only) ----------------

__device__ __forceinline__ int find_root(int* P, int i) {
    int p = P[i];
    while (p != i) {
        int gp = P[p];
        P[i] = gp;   // path halving (benign race)
        i = p;
        p = gp;
    }
    return i;
}

__device__ __forceinline__ void merge(int* P, int a, int b) {
    a = find_root(P, a);
    b = find_root(P, b);
    while (a != b) {
        if (a < b) { int t = a; a = b; b = t; }  // a = larger root
        int old = atomicCAS(&P[a], a, b);        // attach larger under smaller
        if (old == a) return;
        a = find_root(P, old);
        b = find_root(P, b);
    }
}

// ---------------- LDS union-find (merge phase only; no count bits yet) -------

__device__ __forceinline__ int lfind(int* P, int i) {
    int p = P[i];
    while (p != i) {
        int gp = P[p];
        P[i] = gp;
        i = p;
        p = gp;
    }
    return i;
}

__device__ __forceinline__ void lmerge(int* P, int a, int b) {
    a = lfind(P, a);
    b = lfind(P, b);
    while (a != b) {
        if (a < b) { int t = a; a = b; b = t; }
        int old = atomicCAS(&P[a], a, b);
        if (old == a) return;
        a = lfind(P, old);
        b = lfind(P, b);
    }
}

__device__ __forceinline__ ull umax64(ull a, ull b) { return a > b ? a : b; }

// ---------------- kernels ----------------

// per 64x64 tile: argmax -> labels; run-based local CCL in LDS;
// fused flatten+count (counts in sp high bits, one LDS atomic per run).
// writes: labels; parent[pix] = global idx of tile-local root (-1 bg);
//         counts[pix] = local component size at fg local-root pixels, 0 elsewhere.
__global__ __launch_bounds__(CCL_TPB) void k_tile_ccl(
        const float* __restrict__ pred,
        uint8_t* __restrict__ labels,
        int* __restrict__ parent,
        uint32_t* __restrict__ counts,
        ull* __restrict__ best) {
    __shared__ __align__(16) int sp[TPIX];       // 16 KB parent; roots gain count<<16
    __shared__ __align__(16) uint8_t slab[TPIX]; // 4 KB labels (live whole kernel)

    if (blockIdx.x == 0) {
        for (int i = threadIdx.x; i < NIMG * BEST_STRIDE; i += CCL_TPB) best[i] = 0ull;
    }

    const int tid = (int)threadIdx.x;
    const int img = blockIdx.x / TILES_PER_IMG;
    const int tile = blockIdx.x % TILES_PER_IMG;
    const int tr = (tile / TPI) * TS;
    const int tc = (tile % TPI) * TS;
    const float* pb = pred + (size_t)img * CC * HW;
    const int imgbase = img * HW;

    // phase 1: argmax, 4 px/thread; store to slab + global labels
    for (int k = 0; k < TPIX; k += CCL_TPB * 4) {
        int li = k + tid * 4;
        int gi = (tr + (li >> 6)) * WW + tc + (li & 63);
        float4 v0 = *(const float4*)&pb[gi];
        float4 v1 = *(const float4*)&pb[gi + HW];
        float4 v2 = *(const float4*)&pb[gi + 2 * HW];
        float4 v3 = *(const float4*)&pb[gi + 3 * HW];
        const float* a0 = &v0.x; const float* a1 = &v1.x;
        const float* a2 = &v2.x; const float* a3 = &v3.x;
        uchar4 lout;
        uint8_t* lj = &lout.x;
        #pragma unroll
        for (int j = 0; j < 4; ++j) {
            int lab = 0;
            float bv = a0[j];
            if (a1[j] > bv) { bv = a1[j]; lab = 1; }
            if (a2[j] > bv) { bv = a2[j]; lab = 2; }
            if (a3[j] > bv) { bv = a3[j]; lab = 3; }
            lj[j] = (uint8_t)lab;
        }
        *(uchar4*)&slab[li] = lout;
        *(uchar4*)&labels[imgbase + gi] = lout;
    }
    __syncthreads();

    const int c = tid & 63;  // wave lane == column within row

    // phase 2: horizontal runs via ballot; sp[pix] = run-start (fg), self (bg)
    #pragma unroll 1
    for (int it = 0; it < TPIX / CCL_TPB; ++it) {
        int li = it * CCL_TPB + tid;
        int lab = slab[li];
        int labL = __shfl_up(lab, 1, 64);
        bool isStart = lab && (c == 0 || labL != lab);
        ull mask = __ballot(isStart);
        int v = li;
        if (lab) {
            ull mle = mask & (~0ull >> (63 - c));
            v = (li & ~63) + (63 - __clzll(mle));
        }
        sp[li] = v;
    }
    __syncthreads();

    // phase 3: vertical merges, one per run-contact segment (crack criterion)
    #pragma unroll 1
    for (int it = 0; it < TPIX / CCL_TPB; ++it) {
        int li = it * CCL_TPB + tid;
        int lab = slab[li];
        int labU = (li >= TS) ? (int)slab[li - TS] : 0;
        int labL = __shfl_up(lab, 1, 64);
        int labUL = __shfl_up(labU, 1, 64);
        if (lab && labU == lab) {
            if (c == 0 || !(labL == lab && labUL == lab))
                lmerge(sp, li, li - TS);
        }
    }
    __syncthreads();

    // phase 4: fused flatten + run-count.
    // Read-only chase to root (all merges done => roots stable); single
    // owner-write sp[li]=root for non-roots (nobody else writes sp[li]:
    // count atomics target roots only). Run-start lanes add runlen<<16 at root.
    #pragma unroll 1
    for (int it = 0; it < TPIX / CCL_TPB; ++it) {
        int li = it * CCL_TPB + tid;
        int lab = slab[li];
        int labL = __shfl_up(lab, 1, 64);
        bool isStart = lab && (c == 0 || labL != lab);
        bool isEnd = lab && (c == 63 || (int)slab[li + 1] != lab);
        ull endmask = __ballot(isEnd);
        if (lab) {
            int p = sp[li] & 0xFFFF;
            if (p != li) {
                int q0 = sp[p] & 0xFFFF;
                while (q0 != p) { p = q0; q0 = sp[p] & 0xFFFF; }
                sp[li] = p;  // p is the root, clean value
            }
            if (isStart) {
                ull mge = endmask & (~0ull << c);
                int epos = __ffsll((long long)mge) - 1;
                int runlen = epos - c + 1;
                atomicAdd((unsigned int*)&sp[p], (unsigned int)runlen << 16);
            }
        }
    }
    __syncthreads();

    // phase 5: write parent & counts, 4 px/thread
    for (int k = 0; k < TPIX; k += CCL_TPB * 4) {
        int li = k + tid * 4;
        int gi = imgbase + (tr + (li >> 6)) * WW + tc + (li & 63);
        uchar4 lv = *(const uchar4*)&slab[li];
        int4 sv = *(const int4*)&sp[li];
        const uint8_t* lj = &lv.x;
        const int* sj = &sv.x;
        int4 pout; uint4 cout;
        int* pj = &pout.x; uint32_t* cj = &cout.x;
        #pragma unroll
        for (int j = 0; j < 4; ++j) {
            int root = sj[j] & 0xFFFF;
            if (lj[j]) {
                pj[j] = imgbase + (tr + (root >> 6)) * WW + tc + (root & 63);
                cj[j] = (root == li + j) ? ((uint32_t)sj[j] >> 16) : 0u;
            } else {
                pj[j] = -1;
                cj[j] = 0u;
            }
        }
        *(int4*)&parent[gi] = pout;
        *(uint4*)&counts[gi] = cout;
    }
}

// merge across tile borders only
#define VEDGES ((TPI - 1) * HH)             // 8448
#define EDGES_PER_IMG (2 * (TPI - 1) * HH)  // 16896
__global__ void k_border_merge(const uint8_t* __restrict__ labels, int* parent) {
    int t = blockIdx.x * blockDim.x + threadIdx.x;
    if (t >= BB * EDGES_PER_IMG) return;
    int img = t / EDGES_PER_IMG;
    int e = t % EDGES_PER_IMG;
    int a, b;
    if (e < VEDGES) {
        int j = e / HH, r = e % HH;
        int c = j * TS + TS - 1;
        a = r * WW + c;
        b = a + 1;
    } else {
        e -= VEDGES;
        int j = e / WW, c = e % WW;
        int r = j * TS + TS - 1;
        a = r * WW + c;
        b = a + WW;
    }
    int ga = img * HW + a, gb = img * HW + b;
    uint8_t la = labels[ga];
    if (la && labels[gb] == la) merge(parent, ga, gb);
}

// for each local root (counts>0): chase to global root, point parent at it,
// move its local count there. Vectorized scan, early-out on all-zero quads.
__global__ void k_compress(int* __restrict__ parent, uint32_t* __restrict__ counts) {
    int q = blockIdx.x * blockDim.x + threadIdx.x;
    if (q >= NPIX / 4) return;
    int t = q * 4;
    uint4 cv = *(const uint4*)&counts[t];
    if (!(cv.x | cv.y | cv.z | cv.w)) return;
    uint32_t cs[4] = {cv.x, cv.y, cv.z, cv.w};
    #pragma unroll
    for (int j = 0; j < 4; ++j) {
        if (!cs[j]) continue;
        int i = t + j;
        int g = parent[i];
        if (g == i) continue;   // already a global root
        while (true) { int pg = parent[g]; if (pg == g) break; g = pg; }
        parent[i] = g;
        atomicAdd(&counts[g], cs[j]);
        counts[i] = 0;
    }
}

// per (img, class) max over roots of key = (count<<32) | ~root_index
#define BEST_BLK_PER_IMG 144
#define BEST_TPB 256
#define BEST_PIX_PER_BLK (HW / BEST_BLK_PER_IMG)  // 4096
__global__ void k_best(const uint8_t* __restrict__ labels,
                       const uint32_t* __restrict__ counts,
                       ull* __restrict__ best) {
    __shared__ ull sw[(BEST_TPB / 64) * 3];
    int img = blockIdx.x / BEST_BLK_PER_IMG;
    int chunk = blockIdx.x % BEST_BLK_PER_IMG;
    int base = img * HW + chunk * BEST_PIX_PER_BLK;

    ull l0 = 0, l1 = 0, l2 = 0;
    for (int k = 0; k < BEST_PIX_PER_BLK; k += BEST_TPB * 4) {
        int t = base + k + (int)threadIdx.x * 4;
        uint4 cv = *(const uint4*)&counts[t];
        if (cv.x | cv.y | cv.z | cv.w) {
            uchar4 lv = *(const uchar4*)&labels[t];
            uint32_t cs[4] = {cv.x, cv.y, cv.z, cv.w};
            uint8_t ls[4] = {lv.x, lv.y, lv.z, lv.w};
            #pragma unroll
            for (int j = 0; j < 4; ++j) {
                if (cs[j]) {
                    int cc = (int)ls[j] - 1;
                    ull key = ((ull)cs[j] << 32) | (ull)(~(uint32_t)(t + j));
                    if (cc == 0) l0 = umax64(l0, key);
                    else if (cc == 1) l1 = umax64(l1, key);
                    else l2 = umax64(l2, key);
                }
            }
        }
    }
    #pragma unroll
    for (int m = 1; m < 64; m <<= 1) {
        l0 = umax64(l0, __shfl_xor(l0, m, 64));
        l1 = umax64(l1, __shfl_xor(l1, m, 64));
        l2 = umax64(l2, __shfl_xor(l2, m, 64));
    }
    int lane = threadIdx.x & 63;
    int wid = threadIdx.x >> 6;
    if (lane == 0) { sw[wid * 3 + 0] = l0; sw[wid * 3 + 1] = l1; sw[wid * 3 + 2] = l2; }
    __syncthreads();
    if (threadIdx.x < 3) {
        ull m = 0;
        for (int w = 0; w < BEST_TPB / 64; ++w) m = umax64(m, sw[w * 3 + threadIdx.x]);
        if (m) atomicMax(&best[(img * 3 + (int)threadIdx.x) * BEST_STRIDE], m);
    }
}

// final output: global root = parent[parent[t]] (local roots point at global roots)
__global__ void k_output(const uint8_t* __restrict__ labels,
                         const int* __restrict__ parent,
                         const ull* __restrict__ best,
                         float* __restrict__ out) {
    int q = blockIdx.x * blockDim.x + threadIdx.x;
    if (q >= NPIX / 4) return;
    int t = q * 4;
    int b = t / HW;
    int i = t - b * HW;
    uchar4 lv = *(const uchar4*)&labels[t];
    int4 pv = *(const int4*)&parent[t];
    int root[3];
    root[0] = (int)(~(uint32_t)best[(b * 3 + 0) * BEST_STRIDE]);
    root[1] = (int)(~(uint32_t)best[(b * 3 + 1) * BEST_STRIDE]);
    root[2] = (int)(~(uint32_t)best[(b * 3 + 2) * BEST_STRIDE]);

    uint8_t ls[4] = {lv.x, lv.y, lv.z, lv.w};
    int ps[4] = {pv.x, pv.y, pv.z, pv.w};
    float fg[4];
    #pragma unroll
    for (int j = 0; j < 4; ++j) {
        int g = -1;
        if (ps[j] >= 0) g = parent[ps[j]];  // tile-local -> cache hit
        fg[j] = (ls[j] && g == root[ls[j] - 1]) ? 1.0f : 0.0f;
    }

    float4 o0, o1, o2, o3;
    float* c0 = &o0.x; float* c1 = &o1.x; float* c2 = &o2.x; float* c3 = &o3.x;
    #pragma unroll
    for (int j = 0; j < 4; ++j) {
        c0[j] = 1.0f - fg[j];
        c1[j] = (ls[j] == 1) ? fg[j] : 0.0f;
        c2[j] = (ls[j] == 2) ? fg[j] : 0.0f;
        c3[j] = (ls[j] == 3) ? fg[j] : 0.0f;
    }
    float* o = out + (size_t)b * CC * HW + i;
    *(float4*)&o[0] = o0;
    *(float4*)&o[HW] = o1;
    *(float4*)&o[2 * HW] = o2;
    *(float4*)&o[3 * HW] = o3;
}

// ---------------- launch ----------------

extern "C" void kernel_launch(void* const* d_in, const int* in_sizes, int n_in,
                              void* d_out, int out_size, void* d_ws, size_t ws_size,
                              hipStream_t stream) {
    const float* pred = (const float*)d_in[0];
    float* out = (float*)d_out;

    uint8_t* labels = (uint8_t*)d_ws;                            // NPIX bytes
    int* parent = (int*)((char*)d_ws + NPIX);                    // NPIX*4 bytes
    ull* best = (ull*)((char*)d_ws + NPIX + (size_t)NPIX * 4);   // NIMG*BEST_STRIDE*8
    uint32_t* counts = (uint32_t*)d_out;  // reuse d_out; overwritten by k_output

    const int TPB = 256;

    k_tile_ccl<<<BB * TILES_PER_IMG, CCL_TPB, 0, stream>>>(pred, labels, parent, counts, best);
    k_border_merge<<<(BB * EDGES_PER_IMG + TPB - 1) / TPB, TPB, 0, stream>>>(labels, parent);
    k_compress<<<(NPIX / 4 + TPB - 1) / TPB, TPB, 0, stream>>>(parent, counts);
    k_best<<<BB * BEST_BLK_PER_IMG, BEST_TPB, 0, stream>>>(labels, counts, best);
    k_output<<<(NPIX / 4 + TPB - 1) / TPB, TPB, 0, stream>>>(labels, parent, best, out);
}

// Round 9
// 150.103 us; speedup vs baseline: 1.1423x; 1.0272x over previous
//
#include <hip/hip_runtime.h>
#include <stdint.h>

#define BB 16
#define CC 4
#define HH 768
#define WW 768
#define HW (HH * WW)          // 589824
#define NPIX (BB * HW)        // 9437184
#define NIMG (BB * (CC - 1))  // 48
#define BEST_STRIDE 16        // ull entries -> 128 B per (img,class)

#define TS 64                 // tile side
#define TPI (WW / TS)         // 12 tiles per image dim
#define TILES_PER_IMG (TPI * TPI)  // 144
#define TPIX (TS * TS)        // 4096
#define CCL_TPB 256
#define STRIP 16              // rows per wave

typedef unsigned long long ull;

// ---------------- global union-find (border merges only) ----------------

__device__ __forceinline__ int find_root(int* P, int i) {
    int p = P[i];
    while (p != i) {
        int gp = P[p];
        P[i] = gp;   // path halving (benign race)
        i = p;
        p = gp;
    }
    return i;
}

__device__ __forceinline__ void merge(int* P, int a, int b) {
    a = find_root(P, a);
    b = find_root(P, b);
    while (a != b) {
        if (a < b) { int t = a; a = b; b = t; }  // a = larger root
        int old = atomicCAS(&P[a], a, b);        // attach larger under smaller
        if (old == a) return;
        a = find_root(P, old);
        b = find_root(P, b);
    }
}

// ---------------- LDS union-find ----------------

__device__ __forceinline__ int lfind(int* P, int i) {
    int p = P[i];
    while (p != i) {
        int gp = P[p];
        P[i] = gp;
        i = p;
        p = gp;
    }
    return i;
}

__device__ __forceinline__ void lmerge(int* P, int a, int b) {
    a = lfind(P, a);
    b = lfind(P, b);
    while (a != b) {
        if (a < b) { int t = a; a = b; b = t; }
        int old = atomicCAS(&P[a], a, b);
        if (old == a) return;
        a = lfind(P, old);
        b = lfind(P, b);
    }
}

__device__ __forceinline__ ull umax64(ull a, ull b) { return a > b ? a : b; }

// wait for this wave's outstanding LDS ops (incl. all lanes' ds_writes of the
// same instruction), and pin the compiler scheduler
__device__ __forceinline__ void lds_fence() {
    asm volatile("s_waitcnt lgkmcnt(0)" ::: "memory");
    __builtin_amdgcn_sched_barrier(0);
}

// ---------------- kernels ----------------

// per 64x64 tile: argmax -> labels; per-wave strip raster-scan CCL (register-
// carried previous row, no barriers inside strips); cross-strip boundary merge;
// fused flatten+run-count (counts in sp high bits).
// writes: labels; parent[pix] = global idx of tile-local root (-1 bg);
//         counts[pix] = local component size at fg local-root pixels, 0 elsewhere.
__global__ __launch_bounds__(CCL_TPB) void k_tile_ccl(
        const float* __restrict__ pred,
        uint8_t* __restrict__ labels,
        int* __restrict__ parent,
        uint32_t* __restrict__ counts,
        ull* __restrict__ best) {
    __shared__ __align__(16) int sp[TPIX];       // 16 KB parent; roots gain count<<16
    __shared__ __align__(16) uint8_t slab[TPIX]; // 4 KB labels (live whole kernel)

    if (blockIdx.x == 0) {
        for (int i = threadIdx.x; i < NIMG * BEST_STRIDE; i += CCL_TPB) best[i] = 0ull;
    }

    const int tid = (int)threadIdx.x;
    const int img = blockIdx.x / TILES_PER_IMG;
    const int tile = blockIdx.x % TILES_PER_IMG;
    const int tr = (tile / TPI) * TS;
    const int tc = (tile % TPI) * TS;
    const float* pb = pred + (size_t)img * CC * HW;
    const int imgbase = img * HW;

    // phase 1: argmax, 4 px/thread; store to slab + global labels
    for (int k = 0; k < TPIX; k += CCL_TPB * 4) {
        int li = k + tid * 4;
        int gi = (tr + (li >> 6)) * WW + tc + (li & 63);
        float4 v0 = *(const float4*)&pb[gi];
        float4 v1 = *(const float4*)&pb[gi + HW];
        float4 v2 = *(const float4*)&pb[gi + 2 * HW];
        float4 v3 = *(const float4*)&pb[gi + 3 * HW];
        const float* a0 = &v0.x; const float* a1 = &v1.x;
        const float* a2 = &v2.x; const float* a3 = &v3.x;
        uchar4 lout;
        uint8_t* lj = &lout.x;
        #pragma unroll
        for (int j = 0; j < 4; ++j) {
            int lab = 0;
            float bv = a0[j];
            if (a1[j] > bv) { bv = a1[j]; lab = 1; }
            if (a2[j] > bv) { bv = a2[j]; lab = 2; }
            if (a3[j] > bv) { bv = a3[j]; lab = 3; }
            lj[j] = (uint8_t)lab;
        }
        *(uchar4*)&slab[li] = lout;
        *(uchar4*)&labels[imgbase + gi] = lout;
    }
    __syncthreads();

    const int w = tid >> 6;      // wave id: owns rows [16w, 16w+16)
    const int lane = tid & 63;   // column

    // phase 2: per-wave strip raster scan — runs + ordered vertical merges.
    // prevLab/prevV carry row-1's label and run-start in registers.
    {
        int prevLab = 0, prevV = 0;
        #pragma unroll 1
        for (int r = 0; r < STRIP; ++r) {
            int row = (w << 4) + r;
            int li = (row << 6) + lane;
            int lab = slab[li];
            int labL = __shfl_up(lab, 1, 64);
            bool isStart = lab && (lane == 0 || labL != lab);
            ull mask = __ballot(isStart);
            int v = li;
            if (lab) {
                ull mle = mask & (~0ull >> (63 - lane));
                v = (row << 6) + (63 - __clzll(mle));
            }
            sp[li] = v;
            lds_fence();   // run-start entries visible to this wave's lmerges
            if (r > 0) {
                int labUL = __shfl_up(prevLab, 1, 64);
                if (lab && prevLab == lab) {
                    // crack criterion: merge once per run-contact segment
                    if (lane == 0 || !(labL == lab && labUL == lab))
                        lmerge(sp, v, prevV);
                }
            }
            prevLab = lab;
            prevV = v;
        }
    }
    __syncthreads();

    // phase 3: cross-strip boundary merges (rows 16, 32, 48; 192 candidates)
    if (tid < 64 * 3) {
        int row = ((tid >> 6) + 1) << 4;
        int c = tid & 63;
        int li = (row << 6) + c;
        int lab = slab[li];
        int labU = slab[li - TS];
        if (lab && labU == lab) {
            bool seg = true;
            if (c > 0) {
                int labL = slab[li - 1];
                int labUL = slab[li - TS - 1];
                seg = !(labL == lab && labUL == lab);
            }
            if (seg) lmerge(sp, li, li - TS);
        }
    }
    __syncthreads();

    // phase 4: fused flatten + run-count.
    // Read-only chase to root (roots stable); single owner-write sp[li]=root
    // for non-roots; run-start lanes add runlen<<16 at root.
    #pragma unroll 1
    for (int it = 0; it < TPIX / CCL_TPB; ++it) {
        int li = it * CCL_TPB + tid;
        int c = tid & 63;
        int lab = slab[li];
        int labL = __shfl_up(lab, 1, 64);
        bool isStart = lab && (c == 0 || labL != lab);
        bool isEnd = lab && (c == 63 || (int)slab[li + 1] != lab);
        ull endmask = __ballot(isEnd);
        if (lab) {
            int p = sp[li] & 0xFFFF;
            if (p != li) {
                int q0 = sp[p] & 0xFFFF;
                while (q0 != p) { p = q0; q0 = sp[p] & 0xFFFF; }
                sp[li] = p;  // p is the root, clean value
            }
            if (isStart) {
                ull mge = endmask & (~0ull << c);
                int epos = __ffsll((long long)mge) - 1;
                int runlen = epos - c + 1;
                atomicAdd((unsigned int*)&sp[p], (unsigned int)runlen << 16);
            }
        }
    }
    __syncthreads();

    // phase 5: write parent & counts, 4 px/thread
    for (int k = 0; k < TPIX; k += CCL_TPB * 4) {
        int li = k + tid * 4;
        int gi = imgbase + (tr + (li >> 6)) * WW + tc + (li & 63);
        uchar4 lv = *(const uchar4*)&slab[li];
        int4 sv = *(const int4*)&sp[li];
        const uint8_t* lj = &lv.x;
        const int* sj = &sv.x;
        int4 pout; uint4 cout;
        int* pj = &pout.x; uint32_t* cj = &cout.x;
        #pragma unroll
        for (int j = 0; j < 4; ++j) {
            int root = sj[j] & 0xFFFF;
            if (lj[j]) {
                pj[j] = imgbase + (tr + (root >> 6)) * WW + tc + (root & 63);
                cj[j] = (root == li + j) ? ((uint32_t)sj[j] >> 16) : 0u;
            } else {
                pj[j] = -1;
                cj[j] = 0u;
            }
        }
        *(int4*)&parent[gi] = pout;
        *(uint4*)&counts[gi] = cout;
    }
}

// merge across tile borders only
#define VEDGES ((TPI - 1) * HH)             // 8448
#define EDGES_PER_IMG (2 * (TPI - 1) * HH)  // 16896
__global__ void k_border_merge(const uint8_t* __restrict__ labels, int* parent) {
    int t = blockIdx.x * blockDim.x + threadIdx.x;
    if (t >= BB * EDGES_PER_IMG) return;
    int img = t / EDGES_PER_IMG;
    int e = t % EDGES_PER_IMG;
    int a, b;
    if (e < VEDGES) {
        int j = e / HH, r = e % HH;
        int c = j * TS + TS - 1;
        a = r * WW + c;
        b = a + 1;
    } else {
        e -= VEDGES;
        int j = e / WW, c = e % WW;
        int r = j * TS + TS - 1;
        a = r * WW + c;
        b = a + WW;
    }
    int ga = img * HW + a, gb = img * HW + b;
    uint8_t la = labels[ga];
    if (la && labels[gb] == la) merge(parent, ga, gb);
}

// for each local root (counts>0): chase to global root, point parent at it,
// move its local count there. Vectorized scan, early-out on all-zero quads.
__global__ void k_compress(int* __restrict__ parent, uint32_t* __restrict__ counts) {
    int q = blockIdx.x * blockDim.x + threadIdx.x;
    if (q >= NPIX / 4) return;
    int t = q * 4;
    uint4 cv = *(const uint4*)&counts[t];
    if (!(cv.x | cv.y | cv.z | cv.w)) return;
    uint32_t cs[4] = {cv.x, cv.y, cv.z, cv.w};
    #pragma unroll
    for (int j = 0; j < 4; ++j) {
        if (!cs[j]) continue;
        int i = t + j;
        int g = parent[i];
        if (g == i) continue;   // already a global root
        while (true) { int pg = parent[g]; if (pg == g) break; g = pg; }
        parent[i] = g;
        atomicAdd(&counts[g], cs[j]);
        counts[i] = 0;
    }
}

// per (img, class) max over roots of key = (count<<32) | ~root_index
#define BEST_BLK_PER_IMG 144
#define BEST_TPB 256
#define BEST_PIX_PER_BLK (HW / BEST_BLK_PER_IMG)  // 4096
__global__ void k_best(const uint8_t* __restrict__ labels,
                       const uint32_t* __restrict__ counts,
                       ull* __restrict__ best) {
    __shared__ ull sw[(BEST_TPB / 64) * 3];
    int img = blockIdx.x / BEST_BLK_PER_IMG;
    int chunk = blockIdx.x % BEST_BLK_PER_IMG;
    int base = img * HW + chunk * BEST_PIX_PER_BLK;

    ull l0 = 0, l1 = 0, l2 = 0;
    for (int k = 0; k < BEST_PIX_PER_BLK; k += BEST_TPB * 4) {
        int t = base + k + (int)threadIdx.x * 4;
        uint4 cv = *(const uint4*)&counts[t];
        if (cv.x | cv.y | cv.z | cv.w) {
            uchar4 lv = *(const uchar4*)&labels[t];
            uint32_t cs[4] = {cv.x, cv.y, cv.z, cv.w};
            uint8_t ls[4] = {lv.x, lv.y, lv.z, lv.w};
            #pragma unroll
            for (int j = 0; j < 4; ++j) {
                if (cs[j]) {
                    int cc = (int)ls[j] - 1;
                    ull key = ((ull)cs[j] << 32) | (ull)(~(uint32_t)(t + j));
                    if (cc == 0) l0 = umax64(l0, key);
                    else if (cc == 1) l1 = umax64(l1, key);
                    else l2 = umax64(l2, key);
                }
            }
        }
    }
    #pragma unroll
    for (int m = 1; m < 64; m <<= 1) {
        l0 = umax64(l0, __shfl_xor(l0, m, 64));
        l1 = umax64(l1, __shfl_xor(l1, m, 64));
        l2 = umax64(l2, __shfl_xor(l2, m, 64));
    }
    int lane = threadIdx.x & 63;
    int wid = threadIdx.x >> 6;
    if (lane == 0) { sw[wid * 3 + 0] = l0; sw[wid * 3 + 1] = l1; sw[wid * 3 + 2] = l2; }
    __syncthreads();
    if (threadIdx.x < 3) {
        ull m = 0;
        for (int w = 0; w < BEST_TPB / 64; ++w) m = umax64(m, sw[w * 3 + threadIdx.x]);
        if (m) atomicMax(&best[(img * 3 + (int)threadIdx.x) * BEST_STRIDE], m);
    }
}

// final output: global root = parent[parent[t]] (local roots point at global roots)
__global__ void k_output(const uint8_t* __restrict__ labels,
                         const int* __restrict__ parent,
                         const ull* __restrict__ best,
                         float* __restrict__ out) {
    int q = blockIdx.x * blockDim.x + threadIdx.x;
    if (q >= NPIX / 4) return;
    int t = q * 4;
    int b = t / HW;
    int i = t - b * HW;
    uchar4 lv = *(const uchar4*)&labels[t];
    int4 pv = *(const int4*)&parent[t];
    int root[3];
    root[0] = (int)(~(uint32_t)best[(b * 3 + 0) * BEST_STRIDE]);
    root[1] = (int)(~(uint32_t)best[(b * 3 + 1) * BEST_STRIDE]);
    root[2] = (int)(~(uint32_t)best[(b * 3 + 2) * BEST_STRIDE]);

    uint8_t ls[4] = {lv.x, lv.y, lv.z, lv.w};
    int ps[4] = {pv.x, pv.y, pv.z, pv.w};
    float fg[4];
    #pragma unroll
    for (int j = 0; j < 4; ++j) {
        int g = -1;
        if (ps[j] >= 0) g = parent[ps[j]];  // tile-local -> cache hit
        fg[j] = (ls[j] && g == root[ls[j] - 1]) ? 1.0f : 0.0f;
    }

    float4 o0, o1, o2, o3;
    float* c0 = &o0.x; float* c1 = &o1.x; float* c2 = &o2.x; float* c3 = &o3.x;
    #pragma unroll
    for (int j = 0; j < 4; ++j) {
        c0[j] = 1.0f - fg[j];
        c1[j] = (ls[j] == 1) ? fg[j] : 0.0f;
        c2[j] = (ls[j] == 2) ? fg[j] : 0.0f;
        c3[j] = (ls[j] == 3) ? fg[j] : 0.0f;
    }
    float* o = out + (size_t)b * CC * HW + i;
    *(float4*)&o[0] = o0;
    *(float4*)&o[HW] = o1;
    *(float4*)&o[2 * HW] = o2;
    *(float4*)&o[3 * HW] = o3;
}

// ---------------- launch ----------------

extern "C" void kernel_launch(void* const* d_in, const int* in_sizes, int n_in,
                              void* d_out, int out_size, void* d_ws, size_t ws_size,
                              hipStream_t stream) {
    const float* pred = (const float*)d_in[0];
    float* out = (float*)d_out;

    uint8_t* labels = (uint8_t*)d_ws;                            // NPIX bytes
    int* parent = (int*)((char*)d_ws + NPIX);                    // NPIX*4 bytes
    ull* best = (ull*)((char*)d_ws + NPIX + (size_t)NPIX * 4);   // NIMG*BEST_STRIDE*8
    uint32_t* counts = (uint32_t*)d_out;  // reuse d_out; overwritten by k_output

    const int TPB = 256;

    k_tile_ccl<<<BB * TILES_PER_IMG, CCL_TPB, 0, stream>>>(pred, labels, parent, counts, best);
    k_border_merge<<<(BB * EDGES_PER_IMG + TPB - 1) / TPB, TPB, 0, stream>>>(labels, parent);
    k_compress<<<(NPIX / 4 + TPB - 1) / TPB, TPB, 0, stream>>>(parent, counts);
    k_best<<<BB * BEST_BLK_PER_IMG, BEST_TPB, 0, stream>>>(labels, counts, best);
    k_output<<<(NPIX / 4 + TPB - 1) / TPB, TPB, 0, stream>>>(labels, parent, best, out);
}